// Round 3
// baseline (180.168 us; speedup 1.0000x reference)
//
#include <hip/hip_runtime.h>
#include <hip/hip_bf16.h>
#include <stdint.h>

#define NV   65536   // active voxels
#define KOFF 27      // kernel offsets
#define CIN  128
#define COUT 128

typedef __bf16 bf16x8 __attribute__((ext_vector_type(8)));
typedef float  f32x4  __attribute__((ext_vector_type(4)));

__device__ __forceinline__ void async_copy16(void* lds, const void* g) {
    __builtin_amdgcn_global_load_lds(
        (const __attribute__((address_space(1))) void*)g,
        (__attribute__((address_space(3))) void*)lds,
        16, 0, 0);
}

// ---- fused prep kernel --------------------------------------------------
// Three independent jobs partitioned by blockIdx range (no ordering needed):
//   A [0, 4097)        : features f32 -> bf16 x8 (row NV zeroed)
//   B [4097, 5825)     : weight f32 [K][cin][cout] -> bf16 [K][cout][cin]
//   C [5825, 12737)    : nbr build — exploits sorted out_idx[k,:]:
//                        thread p writes nbr[out[p]]=in[p] and gap-fills
//                        (out[p-1], out[p]) with -1. Each slot written once.
#define JOB_A_BLOCKS 4097
#define JOB_B_BLOCKS 1728
#define JOB_C_BLOCKS 6912   // 27 * 65536 / 256

__global__ void k_prep_all(const float* __restrict__ f,
                           uint4* __restrict__ fb4,
                           const float* __restrict__ w,
                           __hip_bfloat16* __restrict__ wt,
                           const int* __restrict__ in_idx,
                           const int* __restrict__ out_idx,
                           int* __restrict__ nbr) {
    const int b = blockIdx.x;
    const int t = threadIdx.x;
    if (b < JOB_A_BLOCKS) {
        // ---- job A: feature cast x8 ----
        int i = b * 256 + t;
        int total8  = (NV + 1) * CIN / 8;
        int nvalid8 = NV * CIN / 8;
        if (i >= total8) return;
        union { uint4 u; __hip_bfloat16 h[8]; } p;
        if (i < nvalid8) {
            const float4* f4 = (const float4*)f;
            float4 a = f4[i * 2];
            float4 c = f4[i * 2 + 1];
            p.h[0] = __float2bfloat16(a.x);
            p.h[1] = __float2bfloat16(a.y);
            p.h[2] = __float2bfloat16(a.z);
            p.h[3] = __float2bfloat16(a.w);
            p.h[4] = __float2bfloat16(c.x);
            p.h[5] = __float2bfloat16(c.y);
            p.h[6] = __float2bfloat16(c.z);
            p.h[7] = __float2bfloat16(c.w);
        } else {
            p.u = make_uint4(0, 0, 0, 0);   // zero row NV
        }
        fb4[i] = p.u;
    } else if (b < JOB_A_BLOCKS + JOB_B_BLOCKS) {
        // ---- job B: weight transpose+cast ----
        int i = (b - JOB_A_BLOCKS) * 256 + t;
        int k    = i >> 14;          // /16384
        int cin  = (i >> 7) & 127;
        int cout = i & 127;
        wt[k * 16384 + cout * 128 + cin] = __float2bfloat16(w[i]);
    } else {
        // ---- job C: nbr build (gap-fill, race-free) ----
        int i = (b - JOB_A_BLOCKS - JOB_B_BLOCKS) * 256 + t;
        int k = i >> 16;            // / NV
        int p = i & (NV - 1);
        const int* ok = out_idx + k * NV;
        int cur  = ok[p];                     // in [0, NV], sorted
        int prev = (p == 0) ? -1 : ok[p - 1];
        int* nb = nbr + k * NV;
        if (cur < NV) nb[cur] = in_idx[k * NV + p];
        for (int j = prev + 1; j < cur && j < NV; ++j) nb[j] = -1;
    }
}

// ---- main gather-GEMM kernel -------------------------------------------
// block = 256 thr (4 waves 2x2), tile = 128 out-rows x 128 out-cols
// per offset k: stage gathered A (128x128 bf16) + Wt_k (128x128 bf16) in LDS,
// 4 k-steps of mfma 16x16x32 bf16. XOR-chunk swizzle for bank conflicts.
// nbr indices for offset k+1 prefetched during compute of offset k.
__global__ __launch_bounds__(256, 2)
void sp_conv_main(const __hip_bfloat16* __restrict__ feats,
                  const __hip_bfloat16* __restrict__ wt,
                  const int* __restrict__ nbr,
                  const float* __restrict__ bias,
                  float* __restrict__ out) {
    __shared__ unsigned char smem[65536];
    unsigned char* smA = smem;           // 32 KB
    unsigned char* smB = smem + 32768;   // 32 KB

    const int t   = threadIdx.x;
    const int bid = blockIdx.x;
    // XCD swizzle: consecutive 64-tile ranges per XCD for L2 gather locality
    const int tile0 = ((bid & 7) * 64 + (bid >> 3)) * 128;

    const int w    = t >> 6;
    const int lane = t & 63;
    const int lr   = lane & 15;
    const int quad = lane >> 4;
    const int m0   = (w >> 1) * 64;
    const int n0   = (w & 1) * 64;

    // staging-side mapping: LDS slot (row = i*16 + t/16, physchunk = t&15)
    // holds global 16B chunk c = (t&15) ^ (row&15)   [row&15 == t/16]
    const int srow   = t >> 4;
    const int sbyte  = ((t & 15) ^ srow) * 16;

    f32x4 acc[4][4] = {};  // zero-init

    const unsigned char* featsB = (const unsigned char*)feats;
    const unsigned char* wtB    = (const unsigned char*)wt;

    // prefetch offset-0 neighbor rows
    int arows[8];
    {
        const int* nbr0 = nbr + tile0;
        #pragma unroll
        for (int i = 0; i < 8; ++i) arows[i] = nbr0[i * 16 + srow];
    }

    for (int k = 0; k < KOFF; ++k) {
        const unsigned char* wk = wtB + (size_t)k * 32768;
        #pragma unroll
        for (int i = 0; i < 8; ++i) {
            unsigned ar = min((unsigned)arows[i], (unsigned)NV);  // -1 -> zero row
            async_copy16(smA + i * 4096 + t * 16,
                         featsB + (size_t)ar * 256 + sbyte);
            async_copy16(smB + i * 4096 + t * 16,
                         wk + (i * 16 + srow) * 256 + sbyte);
        }
        __syncthreads();   // drains vmcnt (global_load_lds) + barrier

        // prefetch next offset's neighbor rows (latency hidden by MFMA phase)
        if (k + 1 < KOFF) {
            const int* nbrn = nbr + (k + 1) * NV + tile0;
            #pragma unroll
            for (int i = 0; i < 8; ++i) arows[i] = nbrn[i * 16 + srow];
        }

        #pragma unroll
        for (int ks = 0; ks < 4; ++ks) {
            bf16x8 af[4], bfr[4];
            #pragma unroll
            for (int mt = 0; mt < 4; ++mt) {
                int row = m0 + mt * 16 + lr;
                int pch = ((ks * 4 + quad) ^ lr) * 16;
                af[mt] = *(const bf16x8*)(smA + row * 256 + pch);
            }
            #pragma unroll
            for (int nt = 0; nt < 4; ++nt) {
                int row = n0 + nt * 16 + lr;
                int pch = ((ks * 4 + quad) ^ lr) * 16;
                bfr[nt] = *(const bf16x8*)(smB + row * 256 + pch);
            }
            #pragma unroll
            for (int mt = 0; mt < 4; ++mt)
                #pragma unroll
                for (int nt = 0; nt < 4; ++nt)
                    acc[mt][nt] = __builtin_amdgcn_mfma_f32_16x16x32_bf16(
                        af[mt], bfr[nt], acc[mt][nt], 0, 0, 0);
        }
        __syncthreads();
    }

    // epilogue: C/D layout col = lane&15, row = quad*4 + reg
    float bv[4];
    #pragma unroll
    for (int nt = 0; nt < 4; ++nt) bv[nt] = bias[n0 + nt * 16 + lr];

    #pragma unroll
    for (int mt = 0; mt < 4; ++mt) {
        #pragma unroll
        for (int nt = 0; nt < 4; ++nt) {
            #pragma unroll
            for (int r = 0; r < 4; ++r) {
                int grow = tile0 + m0 + mt * 16 + quad * 4 + r;
                out[(size_t)grow * COUT + n0 + nt * 16 + lr] =
                    acc[mt][nt][r] + bv[nt];
            }
        }
    }
}

// ---- launch -------------------------------------------------------------

extern "C" void kernel_launch(void* const* d_in, const int* in_sizes, int n_in,
                              void* d_out, int out_size, void* d_ws, size_t ws_size,
                              hipStream_t stream) {
    const float* features = (const float*)d_in[0];   // [N,128] f32
    const float* weight   = (const float*)d_in[1];   // [27,128,128] f32
    const float* bias     = (const float*)d_in[2];   // [128] f32
    const int*   in_idx   = (const int*)d_in[3];     // [27,N] i32
    const int*   out_idx  = (const int*)d_in[4];     // [27,N] i32
    float* out = (float*)d_out;                      // [N,128] f32

    uint8_t* ws = (uint8_t*)d_ws;
    size_t off = 0;
    __hip_bfloat16* feats_bf = (__hip_bfloat16*)(ws + off);       // (N+1)*128*2
    off += (size_t)(NV + 1) * CIN * 2;
    off = (off + 255) & ~(size_t)255;
    __hip_bfloat16* wt_bf = (__hip_bfloat16*)(ws + off);          // 27*128*128*2
    off += (size_t)KOFF * CIN * COUT * 2;
    off = (off + 255) & ~(size_t)255;
    int* nbr = (int*)(ws + off);                                  // 27*N*4

    // single fused prep launch (jobs A+B+C, mutually independent)
    k_prep_all<<<JOB_A_BLOCKS + JOB_B_BLOCKS + JOB_C_BLOCKS, 256, 0, stream>>>(
        features, (uint4*)feats_bf, weight, wt_bf, in_idx, out_idx, nbr);

    // main gather-GEMM: 512 tiles of 128 rows
    sp_conv_main<<<NV / 128, 256, 0, stream>>>(feats_bf, wt_bf, nbr, bias, out);
}

// Round 4
// 167.206 us; speedup vs baseline: 1.0775x; 1.0775x over previous
//
#include <hip/hip_runtime.h>
#include <hip/hip_bf16.h>
#include <stdint.h>

#define NV   65536   // active voxels
#define KOFF 27      // kernel offsets
#define CIN  128
#define COUT 128

typedef __bf16 bf16x8 __attribute__((ext_vector_type(8)));
typedef float  f32x16 __attribute__((ext_vector_type(16)));

__device__ __forceinline__ void async_copy16(void* lds, const void* g) {
    __builtin_amdgcn_global_load_lds(
        (const __attribute__((address_space(1))) void*)g,
        (__attribute__((address_space(3))) void*)lds,
        16, 0, 0);
}

// ---- fused prep kernel --------------------------------------------------
// Jobs partitioned by blockIdx range (mutually independent; nbr memset to
// 0xFF by a prior hipMemsetAsync node on the same stream):
//   A [0, 4097)   : features f32 -> bf16 x8 (row NV zeroed)
//   B [4097,4205) : weight f32 [K][cin][cout] -> bf16 [K][cout][cin],
//                   LDS-tiled 64x64 transpose (both sides coalesced)
//   S [4205,5933) : rulebook scatter x4: nbr[k][out[p]] = in[p]
#define JOB_A_BLOCKS 4097
#define JOB_B_BLOCKS 108    // 27 k * 4 (64x64 tiles)
#define JOB_S_BLOCKS 1728   // 27*65536/4/256

__global__ void k_prep_all(const float* __restrict__ f,
                           uint4* __restrict__ fb4,
                           const float* __restrict__ w,
                           __hip_bfloat16* __restrict__ wt,
                           const int4* __restrict__ in4,
                           const int4* __restrict__ out4,
                           int* __restrict__ nbr) {
    __shared__ float tb[64][65];
    const int b = blockIdx.x;
    const int t = threadIdx.x;
    if (b < JOB_A_BLOCKS) {
        // ---- job A: feature cast x8 ----
        int i = b * 256 + t;
        int total8  = (NV + 1) * CIN / 8;
        int nvalid8 = NV * CIN / 8;
        if (i >= total8) return;
        union { uint4 u; __hip_bfloat16 h[8]; } p;
        if (i < nvalid8) {
            const float4* f4 = (const float4*)f;
            float4 a = f4[i * 2];
            float4 c = f4[i * 2 + 1];
            p.h[0] = __float2bfloat16(a.x);
            p.h[1] = __float2bfloat16(a.y);
            p.h[2] = __float2bfloat16(a.z);
            p.h[3] = __float2bfloat16(a.w);
            p.h[4] = __float2bfloat16(c.x);
            p.h[5] = __float2bfloat16(c.y);
            p.h[6] = __float2bfloat16(c.z);
            p.h[7] = __float2bfloat16(c.w);
        } else {
            p.u = make_uint4(0, 0, 0, 0);   // zero row NV
        }
        fb4[i] = p.u;
    } else if (b < JOB_A_BLOCKS + JOB_B_BLOCKS) {
        // ---- job B: weight transpose+cast, LDS 64x64 tile ----
        int bb = b - JOB_A_BLOCKS;
        int k    = bb >> 2;
        int r0   = ((bb >> 1) & 1) * 64;   // cin tile base
        int c0   = (bb & 1) * 64;          // cout tile base
        const float* wk = w + k * 16384;
        __hip_bfloat16* wtk = wt + k * 16384;
        #pragma unroll
        for (int j = 0; j < 16; ++j) {
            int lrow = j * 4 + (t >> 6);   // cin-in-tile
            int lcol = t & 63;             // cout-in-tile
            tb[lrow][lcol] = wk[(r0 + lrow) * 128 + (c0 + lcol)];
        }
        __syncthreads();
        #pragma unroll
        for (int j = 0; j < 16; ++j) {
            int orow = j * 4 + (t >> 6);   // cout-in-tile
            int ocol = t & 63;             // cin-in-tile
            wtk[(c0 + orow) * 128 + (r0 + ocol)] = __float2bfloat16(tb[ocol][orow]);
        }
    } else {
        // ---- job S: rulebook scatter x4 (out_idx sorted -> near-coalesced) ----
        int i = (b - JOB_A_BLOCKS - JOB_B_BLOCKS) * 256 + t;
        int k = i >> 14;                   // / (NV/4)
        int4 ii = in4[i];
        int4 oo = out4[i];
        int* nb = nbr + k * (NV + 1);      // slot NV = dummy for padded pairs
        nb[oo.x] = ii.x;
        nb[oo.y] = ii.y;
        nb[oo.z] = ii.z;
        nb[oo.w] = ii.w;
    }
}

// ---- main gather-GEMM kernel -------------------------------------------
// block = 256 thr (4 waves 2x2 of 64x64), tile = 128 out-rows x 128 cout.
// Per offset k: stage gathered A (128x128 bf16) + Wt_k (128x128 bf16) in LDS
// via global_load_lds x16, then 8 k-steps of mfma_f32_32x32x16_bf16 (2x2
// 32x32 tiles per wave). XOR-16B-chunk swizzle keeps LDS conflict-free.
// nbr indices for offset k+1 prefetched during compute of offset k.
__global__ __launch_bounds__(256, 2)
void sp_conv_main(const __hip_bfloat16* __restrict__ feats,
                  const __hip_bfloat16* __restrict__ wt,
                  const int* __restrict__ nbr,
                  const float* __restrict__ bias,
                  float* __restrict__ out) {
    __shared__ unsigned char smem[65536];
    unsigned char* smA = smem;           // 32 KB
    unsigned char* smB = smem + 32768;   // 32 KB

    const int t   = threadIdx.x;
    const int bid = blockIdx.x;
    // XCD swizzle: consecutive 64-tile ranges per XCD for L2 gather locality
    const int tile0 = ((bid & 7) * 64 + (bid >> 3)) * 128;

    const int w    = t >> 6;
    const int lane = t & 63;
    const int l31  = lane & 31;
    const int half = lane >> 5;
    const int m0   = (w >> 1) * 64;
    const int n0   = (w & 1) * 64;

    // staging-side mapping: LDS slot (row = i*16 + t/16, physchunk = t&15)
    // holds global 16B chunk c = (t&15) ^ (row&15)
    const int srow   = t >> 4;
    const int sbyte  = ((t & 15) ^ srow) * 16;

    f32x16 acc[2][2] = {};  // zero-init (64 VGPRs)

    const unsigned char* featsB = (const unsigned char*)feats;
    const unsigned char* wtB    = (const unsigned char*)wt;

    // prefetch offset-0 neighbor rows
    int arows[8];
    {
        const int* nbr0 = nbr + tile0;
        #pragma unroll
        for (int i = 0; i < 8; ++i) arows[i] = nbr0[i * 16 + srow];
    }

    for (int k = 0; k < KOFF; ++k) {
        const unsigned char* wk = wtB + (size_t)k * 32768;
        #pragma unroll
        for (int i = 0; i < 8; ++i) {
            unsigned ar = min((unsigned)arows[i], (unsigned)NV);  // -1 -> zero row
            async_copy16(smA + i * 4096 + t * 16,
                         featsB + (size_t)ar * 256 + sbyte);
            async_copy16(smB + i * 4096 + t * 16,
                         wk + (i * 16 + srow) * 256 + sbyte);
        }
        __syncthreads();   // drains vmcnt (global_load_lds) + barrier

        // prefetch next offset's neighbor rows (latency hidden by MFMA phase)
        if (k + 1 < KOFF) {
            const int* nbrn = nbr + (k + 1) * (NV + 1) + tile0;
            #pragma unroll
            for (int i = 0; i < 8; ++i) arows[i] = nbrn[i * 16 + srow];
        }

        // 8 k-steps of K=16; A[m=lane&31][k=half*8+j], B[n=lane&31][k=half*8+j]
        #pragma unroll
        for (int ks = 0; ks < 8; ++ks) {
            const int c = ks * 2 + half;   // 16B chunk index along cin
            bf16x8 af[2], bfr[2];
            #pragma unroll
            for (int mt = 0; mt < 2; ++mt) {
                int row = m0 + mt * 32 + l31;
                af[mt] = *(const bf16x8*)(smA + row * 256 + ((c ^ (row & 15)) * 16));
            }
            #pragma unroll
            for (int nt = 0; nt < 2; ++nt) {
                int row = n0 + nt * 32 + l31;
                bfr[nt] = *(const bf16x8*)(smB + row * 256 + ((c ^ (row & 15)) * 16));
            }
            #pragma unroll
            for (int mt = 0; mt < 2; ++mt)
                #pragma unroll
                for (int nt = 0; nt < 2; ++nt)
                    acc[mt][nt] = __builtin_amdgcn_mfma_f32_32x32x16_bf16(
                        af[mt], bfr[nt], acc[mt][nt], 0, 0, 0);
        }
        __syncthreads();
    }

    // epilogue: C/D layout col = lane&31, row = (reg&3) + 8*(reg>>2) + 4*half
    float bv[2];
    #pragma unroll
    for (int nt = 0; nt < 2; ++nt) bv[nt] = bias[n0 + nt * 32 + l31];

    #pragma unroll
    for (int mt = 0; mt < 2; ++mt) {
        #pragma unroll
        for (int nt = 0; nt < 2; ++nt) {
            #pragma unroll
            for (int r = 0; r < 16; ++r) {
                int rrow = (r & 3) + 8 * (r >> 2) + 4 * half;
                int grow = tile0 + m0 + mt * 32 + rrow;
                out[(size_t)grow * COUT + n0 + nt * 32 + l31] =
                    acc[mt][nt][r] + bv[nt];
            }
        }
    }
}

// ---- launch -------------------------------------------------------------

extern "C" void kernel_launch(void* const* d_in, const int* in_sizes, int n_in,
                              void* d_out, int out_size, void* d_ws, size_t ws_size,
                              hipStream_t stream) {
    const float* features = (const float*)d_in[0];   // [N,128] f32
    const float* weight   = (const float*)d_in[1];   // [27,128,128] f32
    const float* bias     = (const float*)d_in[2];   // [128] f32
    const int*   in_idx   = (const int*)d_in[3];     // [27,N] i32
    const int*   out_idx  = (const int*)d_in[4];     // [27,N] i32
    float* out = (float*)d_out;                      // [N,128] f32

    uint8_t* ws = (uint8_t*)d_ws;
    size_t off = 0;
    __hip_bfloat16* feats_bf = (__hip_bfloat16*)(ws + off);       // (N+1)*128*2
    off += (size_t)(NV + 1) * CIN * 2;
    off = (off + 255) & ~(size_t)255;
    __hip_bfloat16* wt_bf = (__hip_bfloat16*)(ws + off);          // 27*128*128*2
    off += (size_t)KOFF * CIN * COUT * 2;
    off = (off + 255) & ~(size_t)255;
    int* nbr = (int*)(ws + off);                                  // 27*(NV+1)*4

    // init nbr to 0xFFFFFFFF (-1 = "no neighbor"; main clamps to zero row)
    hipMemsetAsync(nbr, 0xFF, (size_t)KOFF * (NV + 1) * 4, stream);

    // fused prep: feature cast + weight transpose + rulebook scatter
    k_prep_all<<<JOB_A_BLOCKS + JOB_B_BLOCKS + JOB_S_BLOCKS, 256, 0, stream>>>(
        features, (uint4*)feats_bf, weight, wt_bf,
        (const int4*)in_idx, (const int4*)out_idx, nbr);

    // main gather-GEMM: 512 tiles of 128 rows
    sp_conv_main<<<NV / 128, 256, 0, stream>>>(feats_bf, wt_bf, nbr, bias, out);
}

// Round 5
// 158.159 us; speedup vs baseline: 1.1392x; 1.0572x over previous
//
#include <hip/hip_runtime.h>
#include <hip/hip_bf16.h>
#include <stdint.h>

#define NV   65536   // active voxels
#define KOFF 27      // kernel offsets
#define CIN  128
#define COUT 128

typedef __bf16 bf16x8 __attribute__((ext_vector_type(8)));
typedef float  f32x4  __attribute__((ext_vector_type(4)));

__device__ __forceinline__ void async_copy16(void* lds, const void* g) {
    __builtin_amdgcn_global_load_lds(
        (const __attribute__((address_space(1))) void*)g,
        (__attribute__((address_space(3))) void*)lds,
        16, 0, 0);
}

// ---- fused prep kernel --------------------------------------------------
// Jobs partitioned by blockIdx range (mutually independent; nbr memset to
// 0xFF by a prior hipMemsetAsync node on the same stream):
//   A [0, 4097)    : features f32 -> bf16 x8 (row NV zeroed)
//   B [4097, 4313) : weight f32 [K][cin][cout] -> bf16 fragment-major:
//                    wfrag chunk c = k*2048 + w*512 + ks*128 + nt*64 + lane,
//                    holding B[n=w*32+nt*16+(lane&15)][cin=ks*32+(lane>>4)*8+j]
//                    -> a wave's (ks,nt) fragment is one contiguous 1 KB run.
//   S [4313, 6041) : rulebook scatter x4: nbr[k][out[p]] = in[p]
#define JOB_A_BLOCKS 4097
#define JOB_B_BLOCKS 216    // 27*4*4*2*64 chunks / 256
#define JOB_S_BLOCKS 1728   // 27*65536/4/256

__global__ void k_prep_all(const float* __restrict__ f,
                           uint4* __restrict__ fb4,
                           const float* __restrict__ w,
                           uint4* __restrict__ wfrag4,
                           const int4* __restrict__ in4,
                           const int4* __restrict__ out4,
                           int* __restrict__ nbr) {
    const int b = blockIdx.x;
    const int t = threadIdx.x;
    if (b < JOB_A_BLOCKS) {
        // ---- job A: feature cast x8 ----
        int i = b * 256 + t;
        int total8  = (NV + 1) * CIN / 8;
        int nvalid8 = NV * CIN / 8;
        if (i >= total8) return;
        union { uint4 u; __hip_bfloat16 h[8]; } p;
        if (i < nvalid8) {
            const float4* f4 = (const float4*)f;
            float4 a = f4[i * 2];
            float4 c = f4[i * 2 + 1];
            p.h[0] = __float2bfloat16(a.x);
            p.h[1] = __float2bfloat16(a.y);
            p.h[2] = __float2bfloat16(a.z);
            p.h[3] = __float2bfloat16(a.w);
            p.h[4] = __float2bfloat16(c.x);
            p.h[5] = __float2bfloat16(c.y);
            p.h[6] = __float2bfloat16(c.z);
            p.h[7] = __float2bfloat16(c.w);
        } else {
            p.u = make_uint4(0, 0, 0, 0);   // zero row NV
        }
        fb4[i] = p.u;
    } else if (b < JOB_A_BLOCKS + JOB_B_BLOCKS) {
        // ---- job B: weight -> fragment-major bf16 ----
        int c    = (b - JOB_A_BLOCKS) * 256 + t;   // chunk index
        int lane = c & 63;
        int nt   = (c >> 6) & 1;
        int ks   = (c >> 7) & 3;
        int wv   = (c >> 9) & 3;
        int k    = c >> 11;
        int cout = wv * 32 + nt * 16 + (lane & 15);
        int cin0 = ks * 32 + (lane >> 4) * 8;
        const float* wk = w + k * 16384;
        union { uint4 u; __hip_bfloat16 h[8]; } p;
        #pragma unroll
        for (int j = 0; j < 8; ++j)
            p.h[j] = __float2bfloat16(wk[(cin0 + j) * 128 + cout]);
        wfrag4[c] = p.u;
    } else {
        // ---- job S: rulebook scatter x4 (out_idx sorted -> near-coalesced) ----
        int i = (b - JOB_A_BLOCKS - JOB_B_BLOCKS) * 256 + t;
        int k = i >> 14;                   // / (NV/4)
        int4 ii = in4[i];
        int4 oo = out4[i];
        int* nb = nbr + k * (NV + 1);      // slot NV = dummy for padded pairs
        nb[oo.x] = ii.x;
        nb[oo.y] = ii.y;
        nb[oo.z] = ii.z;
        nb[oo.w] = ii.w;
    }
}

// ---- main gather-GEMM kernel -------------------------------------------
// block = 256 thr; wave w computes ALL 128 rows x 32-col slice [w*32,w*32+32).
// A: LDS double-buffered (2 x 32 KB); stage A(k+1) issued BEFORE compute(k)
//    so the barrier's vmcnt(0) drain overlaps ~620 cyc of MFMA.
// B: registers, fragment-major coalesced global loads (L2-resident 0.9 MB),
//    prefetched one offset ahead. ONE barrier per offset (27 total).
__global__ __launch_bounds__(256, 2)
void sp_conv_main(const __hip_bfloat16* __restrict__ feats,
                  const uint4* __restrict__ wfrag,
                  const int* __restrict__ nbr,
                  const float* __restrict__ bias,
                  float* __restrict__ out) {
    __shared__ unsigned char smem[65536];   // two 32 KB A buffers

    const int t   = threadIdx.x;
    const int bid = blockIdx.x;
    // XCD swizzle: consecutive 64-tile ranges per XCD for L2 gather locality
    const int tile0 = ((bid & 7) * 64 + (bid >> 3)) * 128;

    const int w    = t >> 6;
    const int lane = t & 63;
    const int lr   = lane & 15;
    const int quad = lane >> 4;

    // staging-side mapping: LDS slot (row = i*16 + t/16, physchunk = t&15)
    // holds global 16B chunk c = (t&15) ^ (row&15)
    const int srow   = t >> 4;
    const int sbyte  = ((t & 15) ^ srow) * 16;

    f32x4 acc[8][2] = {};  // 64 VGPRs

    const unsigned char* featsB = (const unsigned char*)feats;

    // nbr rows for k=0
    int arows[8];
    {
        const int* nbr0 = nbr + tile0;
        #pragma unroll
        for (int i = 0; i < 8; ++i) arows[i] = nbr0[i * 16 + srow];
    }
    // stage A0 into buf 0
    #pragma unroll
    for (int i = 0; i < 8; ++i) {
        unsigned ar = min((unsigned)arows[i], (unsigned)NV);
        async_copy16(smem + i * 4096 + t * 16,
                     featsB + (size_t)ar * 256 + sbyte);
    }
    // prefetch nbr rows for k=1
    {
        const int* nbr1 = nbr + (NV + 1) + tile0;
        #pragma unroll
        for (int i = 0; i < 8; ++i) arows[i] = nbr1[i * 16 + srow];
    }
    // load B fragments for k=0:  chunk = k*2048 + w*512 + ks*128 + nt*64 + lane
    uint4 bcur[4][2], bnext[4][2];
    {
        const uint4* wf0 = wfrag + w * 512 + lane;
        #pragma unroll
        for (int ks = 0; ks < 4; ++ks)
            #pragma unroll
            for (int nt = 0; nt < 2; ++nt)
                bcur[ks][nt] = wf0[ks * 128 + nt * 64];
    }
    __syncthreads();   // A0 staged (vmcnt drain)

    int cbuf = 0;
    for (int k = 0; k < KOFF; ++k) {
        if (k + 1 < KOFF) {
            // issue A(k+1) staging into the idle buffer (overlaps compute)
            unsigned char* dst = smem + (cbuf ^ 1) * 32768;
            #pragma unroll
            for (int i = 0; i < 8; ++i) {
                unsigned ar = min((unsigned)arows[i], (unsigned)NV);
                async_copy16(dst + i * 4096 + t * 16,
                             featsB + (size_t)ar * 256 + sbyte);
            }
            // prefetch nbr rows for k+2
            if (k + 2 < KOFF) {
                const int* nbrn = nbr + (k + 2) * (NV + 1) + tile0;
                #pragma unroll
                for (int i = 0; i < 8; ++i) arows[i] = nbrn[i * 16 + srow];
            }
            // prefetch B(k+1)
            const uint4* wfn = wfrag + (k + 1) * 2048 + w * 512 + lane;
            #pragma unroll
            for (int ks = 0; ks < 4; ++ks)
                #pragma unroll
                for (int nt = 0; nt < 2; ++nt)
                    bnext[ks][nt] = wfn[ks * 128 + nt * 64];
        }

        // compute on buf cbuf with bcur
        const unsigned char* base = smem + cbuf * 32768;
        #pragma unroll
        for (int ks = 0; ks < 4; ++ks) {
            bf16x8 af[8];
            #pragma unroll
            for (int mt = 0; mt < 8; ++mt) {
                int row = mt * 16 + lr;              // row & 15 == lr
                af[mt] = *(const bf16x8*)(base + row * 256 +
                                          (((ks * 4 + quad) ^ lr) * 16));
            }
            #pragma unroll
            for (int mt = 0; mt < 8; ++mt)
                #pragma unroll
                for (int nt = 0; nt < 2; ++nt)
                    acc[mt][nt] = __builtin_amdgcn_mfma_f32_16x16x32_bf16(
                        af[mt], *(const bf16x8*)&bcur[ks][nt],
                        acc[mt][nt], 0, 0, 0);
        }
        __syncthreads();   // waves done with buf cbuf; drains A(k+1) staging
        #pragma unroll
        for (int ks = 0; ks < 4; ++ks)
            #pragma unroll
            for (int nt = 0; nt < 2; ++nt)
                bcur[ks][nt] = bnext[ks][nt];
        cbuf ^= 1;
    }

    // epilogue: C/D layout col = lane&15, row = quad*4 + reg
    const int n0w = w * 32;
    float bv[2];
    #pragma unroll
    for (int nt = 0; nt < 2; ++nt) bv[nt] = bias[n0w + nt * 16 + lr];

    #pragma unroll
    for (int mt = 0; mt < 8; ++mt) {
        #pragma unroll
        for (int nt = 0; nt < 2; ++nt) {
            #pragma unroll
            for (int r = 0; r < 4; ++r) {
                int grow = tile0 + mt * 16 + quad * 4 + r;
                out[(size_t)grow * COUT + n0w + nt * 16 + lr] =
                    acc[mt][nt][r] + bv[nt];
            }
        }
    }
}

// ---- launch -------------------------------------------------------------

extern "C" void kernel_launch(void* const* d_in, const int* in_sizes, int n_in,
                              void* d_out, int out_size, void* d_ws, size_t ws_size,
                              hipStream_t stream) {
    const float* features = (const float*)d_in[0];   // [N,128] f32
    const float* weight   = (const float*)d_in[1];   // [27,128,128] f32
    const float* bias     = (const float*)d_in[2];   // [128] f32
    const int*   in_idx   = (const int*)d_in[3];     // [27,N] i32
    const int*   out_idx  = (const int*)d_in[4];     // [27,N] i32
    float* out = (float*)d_out;                      // [N,128] f32

    uint8_t* ws = (uint8_t*)d_ws;
    size_t off = 0;
    __hip_bfloat16* feats_bf = (__hip_bfloat16*)(ws + off);       // (N+1)*128*2
    off += (size_t)(NV + 1) * CIN * 2;
    off = (off + 255) & ~(size_t)255;
    uint4* wfrag = (uint4*)(ws + off);                            // 27*128*128*2 B
    off += (size_t)KOFF * CIN * COUT * 2;
    off = (off + 255) & ~(size_t)255;
    int* nbr = (int*)(ws + off);                                  // 27*(NV+1)*4

    // init nbr to 0xFFFFFFFF (-1 = "no neighbor"; main clamps to zero row)
    hipMemsetAsync(nbr, 0xFF, (size_t)KOFF * (NV + 1) * 4, stream);

    // fused prep: feature cast + weight fragment-permute + rulebook scatter
    k_prep_all<<<JOB_A_BLOCKS + JOB_B_BLOCKS + JOB_S_BLOCKS, 256, 0, stream>>>(
        features, (uint4*)feats_bf, weight, wfrag,
        (const int4*)in_idx, (const int4*)out_idx, nbr);

    // main gather-GEMM: 512 tiles of 128 rows
    sp_conv_main<<<NV / 128, 256, 0, stream>>>(feats_bf, wfrag, nbr, bias, out);
}